// Round 2
// baseline (17000.592 us; speedup 1.0000x reference)
//
#include <hip/hip_runtime.h>

// FPS (B=32, N=65536, S=512) + gather (C=64), fp32.
//
// Round-2 structure: 8 blocks per batch (256 blocks total = 1 per CU).
// Each block keeps its 8192-point chunk AND its dist array entirely in
// registers (16 pts/thread @ 512 threads -> 64 VGPRs), so the per-iteration
// distance pass is pure VALU. Cross-block argmax per iteration uses a
// device-scope u64 atomicMax slot (value<<32 | ~idx  => max value, min index
// on ties == numpy first-index argmax, valid since dist >= 0) plus a
// monotone arrival counter all blocks spin on. All 256 blocks are
// co-resident (1 block/CU, tiny LDS/VGPR), so the spin cannot deadlock.
//
// Bit-exactness: d = ((dx*dx + dy*dy) + dz*dz) via __fmul_rn/__fadd_rn
// (no fma contraction), fminf for the min -> indices match numpy exactly,
// outputs are bit-equal gathers.

#define BATCH 32
#define NPTS  65536
#define NSAMP 512
#define NCH   64
#define NBLK_PER_B 8
#define TPB   512
#define CHUNK (NPTS / NBLK_PER_B)   // 8192
#define PPT   (CHUNK / TPB)         // 16 points per thread
#define NWAVE (TPB / 64)            // 8

__global__ __launch_bounds__(TPB) void fps_kernel(
    const float* __restrict__ xyz,             // [B, N, 3]
    unsigned long long* __restrict__ slots,    // [B, S]   (memset 0)
    unsigned int* __restrict__ cnts)           // [B * 32] (memset 0, 128B stride)
{
    const int bx    = blockIdx.x;
    const int b     = bx & (BATCH - 1);   // batch
    const int chunk = bx >> 5;            // 0..7
    const int tid   = threadIdx.x;
    const float* xb = xyz + (size_t)b * NPTS * 3;
    const int base  = chunk * CHUNK;

    // Chunk resident in registers.
    float px[PPT], py[PPT], pz[PPT], dist[PPT];
#pragma unroll
    for (int i = 0; i < PPT; ++i) {
        int n = base + i * TPB + tid;
        const float* p = xb + (size_t)n * 3;
        px[i] = p[0]; py[i] = p[1]; pz[i] = p[2];
        dist[i] = 1e10f;
    }

    __shared__ float red_v[NWAVE];
    __shared__ int   red_n[NWAVE];

    unsigned long long* slot_b = slots + (size_t)b * NSAMP;
    unsigned int*       cnt_b  = cnts + b * 32;

    // farthest starts at index 0
    float cx = xb[0], cy = xb[1], cz = xb[2];

    for (int s = 0; s < NSAMP; ++s) {
        // ---- distance update + per-thread argmax (first-index via strict >) ----
        float bv = -1.0f;
        int   bn = 0;
#pragma unroll
        for (int i = 0; i < PPT; ++i) {
            float dx = px[i] - cx;
            float dy = py[i] - cy;
            float dz = pz[i] - cz;
            float d  = __fadd_rn(__fadd_rn(__fmul_rn(dx, dx), __fmul_rn(dy, dy)),
                                 __fmul_rn(dz, dz));
            float nd = fminf(dist[i], d);
            dist[i] = nd;
            if (nd > bv) { bv = nd; bn = base + i * TPB + tid; }
        }

        // ---- wave reduce (max value, min index on ties) ----
#pragma unroll
        for (int off = 32; off >= 1; off >>= 1) {
            float pv = __shfl_down(bv, off, 64);
            int   pn = __shfl_down(bn, off, 64);
            if (pv > bv || (pv == bv && pn < bn)) { bv = pv; bn = pn; }
        }
        const int w = tid >> 6;
        if ((tid & 63) == 0) { red_v[w] = bv; red_n[w] = bn; }
        __syncthreads();

        // ---- block reduce + cross-block publish ----
        if (tid == 0) {
            float fv = red_v[0]; int fn = red_n[0];
#pragma unroll
            for (int i = 1; i < NWAVE; ++i) {
                float pv = red_v[i]; int pn = red_n[i];
                if (pv > fv || (pv == fv && pn < fn)) { fv = pv; fn = pn; }
            }
            unsigned long long packed =
                ((unsigned long long)__float_as_uint(fv) << 32) |
                (unsigned int)(~fn);
            __hip_atomic_fetch_max(&slot_b[s], packed,
                                   __ATOMIC_RELAXED, __HIP_MEMORY_SCOPE_AGENT);
            __hip_atomic_fetch_add(cnt_b, 1u,
                                   __ATOMIC_RELEASE, __HIP_MEMORY_SCOPE_AGENT);
        }

        // ---- all threads spin until all 8 blocks of this batch arrived ----
        const unsigned int target = (unsigned int)(s + 1) * NBLK_PER_B;
        while (__hip_atomic_load(cnt_b, __ATOMIC_RELAXED,
                                 __HIP_MEMORY_SCOPE_AGENT) < target) {
            __builtin_amdgcn_s_sleep(1);
        }
        __threadfence();   // acquire: make winning slot (and its maxes) visible

        unsigned long long win =
            __hip_atomic_load(&slot_b[s], __ATOMIC_RELAXED,
                              __HIP_MEMORY_SCOPE_AGENT);
        int far = (int)(~(unsigned int)win);
        const float* cp = xb + (size_t)far * 3;   // same addr all lanes -> broadcast
        cx = cp[0]; cy = cp[1]; cz = cp[2];
        // No trailing __syncthreads needed: a wave only reaches its next
        // red_* write after the spin, which requires thread 0's arrival add,
        // which is program-ordered after thread 0's red_* reads.
    }
}

// idx[b][0] = 0; idx[b][s] = ~(u32)slot[b][s-1]  (scan carry semantics).
__global__ __launch_bounds__(256) void gather_kernel(
    const float* __restrict__ xyz,   // [B, N, 3]
    const float* __restrict__ f,     // [B, N, C]
    const unsigned long long* __restrict__ slots,  // [B, S]
    float* __restrict__ out_xyz,     // [B, S, 3]
    float* __restrict__ out_f)       // [B, S, C]
{
    const int t  = threadIdx.x;
    const int g  = blockIdx.x * 4 + (t >> 6);   // global sample id, 4 per block
    const int ln = t & 63;
    const int b  = g >> 9;      // / NSAMP
    const int s  = g & (NSAMP - 1);

    int n = 0;
    if (s != 0) n = (int)(~(unsigned int)slots[(size_t)b * NSAMP + (s - 1)]);

    out_f[((size_t)b * NSAMP + s) * NCH + ln] = f[((size_t)b * NPTS + n) * NCH + ln];
    if (ln < 3)
        out_xyz[((size_t)b * NSAMP + s) * 3 + ln] =
            xyz[((size_t)b * NPTS + n) * 3 + ln];
}

extern "C" void kernel_launch(void* const* d_in, const int* in_sizes, int n_in,
                              void* d_out, int out_size, void* d_ws, size_t ws_size,
                              hipStream_t stream) {
    const float* xyz = (const float*)d_in[0];   // [32, 65536, 3]
    const float* f   = (const float*)d_in[1];   // [32, 65536, 64]
    float* out_xyz = (float*)d_out;                               // [32, 512, 3]
    float* out_f   = (float*)d_out + (size_t)BATCH * NSAMP * 3;   // [32, 512, 64]

    unsigned long long* slots = (unsigned long long*)d_ws;        // 128 KiB
    unsigned int* cnts = (unsigned int*)((char*)d_ws + (size_t)BATCH * NSAMP * 8);

    size_t comm_bytes = (size_t)BATCH * NSAMP * 8 + (size_t)BATCH * 32 * 4;
    hipMemsetAsync(d_ws, 0, comm_bytes, stream);

    fps_kernel<<<BATCH * NBLK_PER_B, TPB, 0, stream>>>(xyz, slots, cnts);
    gather_kernel<<<BATCH * NSAMP / 4, 256, 0, stream>>>(xyz, f, slots,
                                                         out_xyz, out_f);
}

// Round 3
// 1740.312 us; speedup vs baseline: 9.7687x; 9.7687x over previous
//
#include <hip/hip_runtime.h>

// FPS (B=32, N=65536, S=512) + gather (C=64), fp32.
//
// Round-3: 8 blocks/batch (256 blocks = 1/CU). Each block's 8192-pt chunk and
// dist array live in REGISTERS (forced via __launch_bounds__(512,1); round 2's
// 48-VGPR allocation proved the default cap demotes the arrays to scratch).
// Per-iteration cross-block argmax: each block stores its packed best
// (dist_bits<<32 | ~idx  -> u64 max == max dist, first index on ties) into its
// own slot of an 8-slot cacheline with a relaxed agent-scope store; wave 0
// polls the 8 slots until all nonzero (packed is always nonzero: ~idx has high
// bits set for idx<65536), max-reduces, and broadcasts the centroid via LDS.
//
// Bit-exactness: d = ((dx*dx + dy*dy) + dz*dz) via __fmul_rn/__fadd_rn (no fma
// contraction), fminf -> indices match numpy argmax exactly.

#define BATCH 32
#define NPTS  65536
#define NSAMP 512
#define NCH   64
#define NBLK_PER_B 8
#define TPB   512
#define CHUNK (NPTS / NBLK_PER_B)   // 8192
#define PPT   (CHUNK / TPB)         // 16
#define NWAVE (TPB / 64)            // 8

__global__ __launch_bounds__(TPB, 1) void fps_kernel(
    const float* __restrict__ xyz,             // [B, N, 3]
    unsigned long long* __restrict__ slots,    // [B, S, 8]  (memset 0)
    int* __restrict__ winners)                 // [B, S]; winners[b][s] = idx[s+1]
{
    const int bx    = blockIdx.x;
    const int b     = bx & (BATCH - 1);
    const int chunk = bx >> 5;                 // 0..7
    const int tid   = threadIdx.x;
    const float* xb = xyz + (size_t)b * NPTS * 3;
    const int base  = chunk * CHUNK;

    float px[PPT], py[PPT], pz[PPT], dist[PPT];
#pragma unroll
    for (int i = 0; i < PPT; ++i) {
        int n = base + i * TPB + tid;
        const float* p = xb + (size_t)n * 3;
        px[i] = p[0]; py[i] = p[1]; pz[i] = p[2];
        dist[i] = 1e10f;
    }

    __shared__ float red_v[NWAVE];
    __shared__ int   red_n[NWAVE];
    __shared__ float cxyz[3];

    unsigned long long* slot_b = slots + (size_t)b * NSAMP * NBLK_PER_B;
    int* win_b = winners + b * NSAMP;

    float cx = xb[0], cy = xb[1], cz = xb[2];

    for (int s = 0; s < NSAMP - 1; ++s) {       // 511 iters; idx[0]=0 implicit
        // ---- dist update + per-thread first-index argmax ----
        float bv = -1.0f;
        int   bn = 0;
#pragma unroll
        for (int i = 0; i < PPT; ++i) {
            float dx = px[i] - cx;
            float dy = py[i] - cy;
            float dz = pz[i] - cz;
            float d  = __fadd_rn(__fadd_rn(__fmul_rn(dx, dx), __fmul_rn(dy, dy)),
                                 __fmul_rn(dz, dz));
            float nd = fminf(dist[i], d);
            dist[i] = nd;
            if (nd > bv) { bv = nd; bn = base + i * TPB + tid; }
        }
        // ---- wave reduce (max value, min index on ties) ----
#pragma unroll
        for (int off = 32; off >= 1; off >>= 1) {
            float pv = __shfl_down(bv, off, 64);
            int   pn = __shfl_down(bn, off, 64);
            if (pv > bv || (pv == bv && pn < bn)) { bv = pv; bn = pn; }
        }
        if ((tid & 63) == 0) { red_v[tid >> 6] = bv; red_n[tid >> 6] = bn; }
        __syncthreads();

        // ---- wave 0: block reduce, publish, poll, winner, centroid ----
        if (tid < 64) {
            float fv = (tid < NWAVE) ? red_v[tid] : -1.0f;
            int   fn = (tid < NWAVE) ? red_n[tid] : 0x7fffffff;
#pragma unroll
            for (int off = 4; off >= 1; off >>= 1) {
                float pv = __shfl_xor(fv, off, 64);
                int   pn = __shfl_xor(fn, off, 64);
                if (pv > fv || (pv == fv && pn < fn)) { fv = pv; fn = pn; }
            }
            unsigned long long* line = slot_b + (size_t)s * NBLK_PER_B;
            if (tid == 0) {
                unsigned long long packed =
                    ((unsigned long long)__float_as_uint(fv) << 32) |
                    (unsigned int)(~fn);
                __hip_atomic_store(&line[chunk], packed,
                                   __ATOMIC_RELAXED, __HIP_MEMORY_SCOPE_AGENT);
            }
            // poll the 8-slot cacheline (lanes >=8 duplicate slot 7)
            const int li = (tid < NBLK_PER_B) ? tid : (NBLK_PER_B - 1);
            unsigned long long v;
            for (;;) {
                v = __hip_atomic_load(&line[li], __ATOMIC_RELAXED,
                                      __HIP_MEMORY_SCOPE_AGENT);
                if (__all(v != 0)) break;
                __builtin_amdgcn_s_sleep(1);
            }
            // u64 max over lanes 0..7 (packed order == desired order)
#pragma unroll
            for (int off = 4; off >= 1; off >>= 1) {
                unsigned long long pv = __shfl_xor(v, off, 64);
                if (pv > v) v = pv;
            }
            if (tid == 0) {
                int far = (int)(~(unsigned int)v);
                if (chunk == 0) win_b[s] = far;            // idx[s+1]
                const float* cp = xb + (size_t)far * 3;    // immutable -> cached
                cxyz[0] = cp[0]; cxyz[1] = cp[1]; cxyz[2] = cp[2];
            }
        }
        __syncthreads();
        cx = cxyz[0]; cy = cxyz[1]; cz = cxyz[2];
    }
}

// idx[b][0] = 0; idx[b][s] = winners[b][s-1] for s >= 1.
__global__ __launch_bounds__(256) void gather_kernel(
    const float* __restrict__ xyz,   // [B, N, 3]
    const float* __restrict__ f,     // [B, N, C]
    const int* __restrict__ winners, // [B, S]
    float* __restrict__ out_xyz,     // [B, S, 3]
    float* __restrict__ out_f)       // [B, S, C]
{
    const int t  = threadIdx.x;
    const int g  = blockIdx.x * 4 + (t >> 6);
    const int ln = t & 63;
    const int b  = g >> 9;
    const int s  = g & (NSAMP - 1);

    int n = (s == 0) ? 0 : winners[b * NSAMP + (s - 1)];

    out_f[((size_t)b * NSAMP + s) * NCH + ln] = f[((size_t)b * NPTS + n) * NCH + ln];
    if (ln < 3)
        out_xyz[((size_t)b * NSAMP + s) * 3 + ln] =
            xyz[((size_t)b * NPTS + n) * 3 + ln];
}

extern "C" void kernel_launch(void* const* d_in, const int* in_sizes, int n_in,
                              void* d_out, int out_size, void* d_ws, size_t ws_size,
                              hipStream_t stream) {
    const float* xyz = (const float*)d_in[0];   // [32, 65536, 3]
    const float* f   = (const float*)d_in[1];   // [32, 65536, 64]
    float* out_xyz = (float*)d_out;                               // [32, 512, 3]
    float* out_f   = (float*)d_out + (size_t)BATCH * NSAMP * 3;   // [32, 512, 64]

    unsigned long long* slots = (unsigned long long*)d_ws;        // 1 MiB
    int* winners = (int*)((char*)d_ws +
                          (size_t)BATCH * NSAMP * NBLK_PER_B * 8);

    hipMemsetAsync(d_ws, 0, (size_t)BATCH * NSAMP * NBLK_PER_B * 8, stream);

    fps_kernel<<<BATCH * NBLK_PER_B, TPB, 0, stream>>>(xyz, slots, winners);
    gather_kernel<<<BATCH * NSAMP / 4, 256, 0, stream>>>(xyz, f, winners,
                                                         out_xyz, out_f);
}